// Round 7
// baseline (2898.949 us; speedup 1.0000x reference)
//
#include <hip/hip_runtime.h>

// LSTM B=4096, T=512, D=H=25, 3 layers + MLP head + softmax.
// R7: in-block LAYER PIPELINE. One block = one batch, 6 waves = 3 layers x
// {role A (rows 0..49 = i,f + updater), role B (rows 50..99 = g,o)}.
// Layer l at global step s runs its timestep t = s-l (skew 1): l's updater
// writes h_{t-1} straight into layer l+1's input LDS slot -> NO ws round-trip
// (R1-R6 wrote+read 410MB+100MB of HBM), weights loaded ONCE, 2 LDS-only
// barriers per global step (0.67 per layer-timestep).
// Phase structure (races checked):
//   phase1: update h_{t-1} from act4[p^1]; write own vec.h[p], handoff
//           vec_{l+1}.x[p]; L0 stager writes x_t -> vec_0.x[p]
//   B1 (lgkmcnt-only barrier)
//   phase2: dot over vec[p] (13 broadcast b128 + 26 pk_fma), activation,
//           write act4[p]
//   B2
// All cross-wave handoffs cross exactly one barrier; same-wave write->read
// is program-order safe; act4[p] consumed at phase1 of s+1 (crosses B2).

typedef float f32x2 __attribute__((ext_vector_type(2)));
typedef float f32x4 __attribute__((ext_vector_type(4)));

#define NT 512
#define ND 25

__device__ __forceinline__ float exp2f_(float x) { return __builtin_amdgcn_exp2f(x); }
__device__ __forceinline__ float rcpf_(float x)  { return __builtin_amdgcn_rcpf(x); }
__device__ __forceinline__ float tanhfast(float x) {
    float s = rcpf_(1.f + exp2f_(-2.885390082f * x));
    return fmaf(2.f, s, -1.f);
}
__device__ __forceinline__ float rdlane(float v, int i) {
    return __uint_as_float(__builtin_amdgcn_readlane(__float_as_uint(v), i));
}
__device__ __forceinline__ void pkfma(f32x2& a, f32x2 w, f32x2 v) {
    asm("v_pk_fma_f32 %0, %1, %2, %0" : "+v"(a) : "v"(w), "v"(v));
}
#define LO2(v) __builtin_shufflevector(v, v, 0, 1)
#define HI2(v) __builtin_shufflevector(v, v, 2, 3)
#define LDSBAR() asm volatile("s_waitcnt lgkmcnt(0)\n\ts_barrier" ::: "memory")

__global__ __launch_bounds__(384, 4)
void lstm7(const float* __restrict__ xin,
           const float* __restrict__ Wih,
           const float* __restrict__ Whh,
           const float* __restrict__ bih,
           const float* __restrict__ bhh,
           const float* __restrict__ W1,
           const float* __restrict__ b1,
           const float* __restrict__ W2,
           const float* __restrict__ b2,
           float* __restrict__ out)
{
    // vec[l][p][0..24]=input x (or h of layer l-1), [25]=0 pad,
    //            [26..50]=own h, [51]=0 pad, [52..55] unused.
    __shared__ __align__(16) float vec[3][2][56];
    // act4[l][p][unit][i,f,g,o]
    __shared__ __align__(16) float act4[3][2][25][4];

    const int wid  = threadIdx.x >> 6;     // 0..5
    const int lane = threadIdx.x & 63;
    const int l    = wid >> 1;             // layer 0..2
    const int role = wid & 1;              // 0: i,f + updater   1: g,o (+L0 stager)
    const int b    = blockIdx.x;

    const int lrow = (lane < 50) ? lane : 49;   // lanes 50-63 duplicate row 49
    const int row  = l * 100 + role * 50 + lrow;
    const float* wihp = Wih + row * ND;
    const float* whhp = Whh + row * ND;

    // ---- 26 packed weight pairs: floats (2k,2k+1) of [x(25),0,h(25),0] ----
    f32x2 wp0  = {wihp[0],  wihp[1]},  wp1  = {wihp[2],  wihp[3]};
    f32x2 wp2  = {wihp[4],  wihp[5]},  wp3  = {wihp[6],  wihp[7]};
    f32x2 wp4  = {wihp[8],  wihp[9]},  wp5  = {wihp[10], wihp[11]};
    f32x2 wp6  = {wihp[12], wihp[13]}, wp7  = {wihp[14], wihp[15]};
    f32x2 wp8  = {wihp[16], wihp[17]}, wp9  = {wihp[18], wihp[19]};
    f32x2 wp10 = {wihp[20], wihp[21]}, wp11 = {wihp[22], wihp[23]};
    f32x2 wp12 = {wihp[24], 0.f};
    f32x2 wp13 = {whhp[0],  whhp[1]},  wp14 = {whhp[2],  whhp[3]};
    f32x2 wp15 = {whhp[4],  whhp[5]},  wp16 = {whhp[6],  whhp[7]};
    f32x2 wp17 = {whhp[8],  whhp[9]},  wp18 = {whhp[10], whhp[11]};
    f32x2 wp19 = {whhp[12], whhp[13]}, wp20 = {whhp[14], whhp[15]};
    f32x2 wp21 = {whhp[16], whhp[17]}, wp22 = {whhp[18], whhp[19]};
    f32x2 wp23 = {whhp[20], whhp[21]}, wp24 = {whhp[22], whhp[23]};
    f32x2 wp25 = {whhp[24], 0.f};
    const float bias = bih[row] + bhh[row];

    // activation constants (wave-uniform-ish, hoisted)
    const bool  isg    = (role == 1) && (lane < ND);
    const float emul   = isg ? -2.885390082f : -1.442695041f;
    const float ascale = isg ?  2.0f : 1.0f;
    const float abias  = isg ? -1.0f : 0.0f;

    // act4 write slot / update read unit
    const int ul   = (lrow >= ND) ? lrow - ND : lrow;
    const int slot = role * 2 + (lrow >= ND ? 1 : 0);
    const int uu   = (lane < ND) ? lane : ND - 1;

    // zero all of vec (incl. h-parts and pads, both parities)
    if (threadIdx.x < 3 * 2 * 56) ((float*)vec)[threadIdx.x] = 0.f;
    __syncthreads();

    const float* srcx = xin + (size_t)b * NT * ND;
    const bool stager = (l == 0) && (role == 1) && (lane < ND);
    float xv_cur = 0.f, xv_nxt = 0.f;
    if (stager) { xv_cur = srcx[lane]; xv_nxt = srcx[ND + lane]; }

    float c = 0.f, hreg = 0.f;

    for (int s = 0; s < NT + 3; ++s) {
        const int p = s & 1;
        const int t = s - l;                      // this layer's dot timestep
        float* const vp = &vec[l][p][0];

        // ---------------- phase 1: update / stage ----------------
        if (role == 0) {
            if (t >= 1 && t <= NT) {              // compute h_{t-1}
                const f32x4 q = *(const f32x4*)&act4[l][p ^ 1][uu][0];
                c = fmaf(q.y, c, q.x * q.z);
                hreg = q.w * tanhfast(c);
                if (lane < ND) {
                    vp[26 + lane] = hreg;         // own h for this step's dot
                    if (l < 2) vec[l + 1][p][lane] = hreg;   // handoff = next layer's x
                }
            }
        } else if (l == 0) {
            if (lane < ND && s < NT) {            // stage x_s
                vp[lane] = xv_cur;
                xv_cur = xv_nxt;
                if (s + 2 < NT) xv_nxt = srcx[(size_t)(s + 2) * ND + lane];
            }
        }
        LDSBAR();   // B1

        // ---------------- phase 2: dot + activation ----------------
        if (t >= 0 && t < NT) {
            const f32x4* const vv = (const f32x4*)vp;
            const f32x4 v0 = vv[0],  v1 = vv[1],  v2 = vv[2],  v3 = vv[3];
            const f32x4 v4 = vv[4],  v5 = vv[5],  v6 = vv[6],  v7 = vv[7];
            const f32x4 v8 = vv[8],  v9 = vv[9],  v10 = vv[10], v11 = vv[11];
            const f32x4 v12 = vv[12];
            f32x2 A0 = {bias, 0.f}, A1 = {0.f, 0.f}, A2 = {0.f, 0.f}, A3 = {0.f, 0.f};
            pkfma(A0, wp0,  LO2(v0));  pkfma(A1, wp1,  HI2(v0));
            pkfma(A2, wp2,  LO2(v1));  pkfma(A3, wp3,  HI2(v1));
            pkfma(A0, wp4,  LO2(v2));  pkfma(A1, wp5,  HI2(v2));
            pkfma(A2, wp6,  LO2(v3));  pkfma(A3, wp7,  HI2(v3));
            pkfma(A0, wp8,  LO2(v4));  pkfma(A1, wp9,  HI2(v4));
            pkfma(A2, wp10, LO2(v5));  pkfma(A3, wp11, HI2(v5));
            pkfma(A0, wp12, LO2(v6));  pkfma(A1, wp13, HI2(v6));
            pkfma(A2, wp14, LO2(v7));  pkfma(A3, wp15, HI2(v7));
            pkfma(A0, wp16, LO2(v8));  pkfma(A1, wp17, HI2(v8));
            pkfma(A2, wp18, LO2(v9));  pkfma(A3, wp19, HI2(v9));
            pkfma(A0, wp20, LO2(v10)); pkfma(A1, wp21, HI2(v10));
            pkfma(A2, wp22, LO2(v11)); pkfma(A3, wp23, HI2(v11));
            pkfma(A0, wp24, LO2(v12)); pkfma(A1, wp25, HI2(v12));
            A0 = A0 + A1; A2 = A2 + A3; A0 = A0 + A2;
            const float acc = A0.x + A0.y;

            const float a = fmaf(ascale, rcpf_(1.f + exp2f_(emul * acc)), abias);
            if (lane < 50) act4[l][p][ul][slot] = a;
        }
        LDSBAR();   // B2
    }

    // ---- head (wave l=2, role A): relu(h W1^T+b1) W2^T+b2, softmax(14) ----
    if (l == 2 && role == 0) {
        const int hl = (lane < 16) ? lane : 15;
        float u = b1[hl];
#pragma unroll
        for (int d = 0; d < ND; ++d)
            u = fmaf(W1[hl * ND + d], rdlane(hreg, d), u);
        u = fmaxf(u, 0.f);

        const int cl = (lane < 14) ? lane : 13;
        float lg = b2[cl];
#pragma unroll
        for (int r = 0; r < 16; ++r)
            lg = fmaf(W2[cl * 16 + r], rdlane(u, r), lg);

        float m = -1e30f;
#pragma unroll
        for (int j = 0; j < 14; ++j) m = fmaxf(m, rdlane(lg, j));
        float sum = 0.f;
#pragma unroll
        for (int j = 0; j < 14; ++j)
            sum += exp2f_(1.442695041f * (rdlane(lg, j) - m));
        const float pr = exp2f_(1.442695041f * (lg - m)) * rcpf_(sum);
        if (lane < 14) out[b * 14 + lane] = pr;
    }
}

extern "C" void kernel_launch(void* const* d_in, const int* in_sizes, int n_in,
                              void* d_out, int out_size, void* d_ws, size_t ws_size,
                              hipStream_t stream)
{
    const float* x   = (const float*)d_in[0];
    const float* Wih = (const float*)d_in[1];
    const float* Whh = (const float*)d_in[2];
    const float* bih = (const float*)d_in[3];
    const float* bhh = (const float*)d_in[4];
    const float* W1  = (const float*)d_in[5];
    const float* b1  = (const float*)d_in[6];
    const float* W2  = (const float*)d_in[7];
    const float* b2  = (const float*)d_in[8];
    float* outp = (float*)d_out;
    (void)d_ws; (void)ws_size;   // no global scratch needed anymore

    dim3 grid(4096), block(384);
    hipLaunchKernelGGL(lstm7, grid, block, 0, stream,
                       x, Wih, Whh, bih, bhh, W1, b1, W2, b2, outp);
}